// Round 22
// baseline (98.121 us; speedup 1.0000x reference)
//
#include <hip/hip_runtime.h>

// ---------------------------------------------------------------------------
// CausalSelfAttention: fake-quant-i4 weights -> QKV gemm (64x128 tile, fused
// RMSNorm+RoPE+gain epilogue, XCD swizzle) -> GQA causal flash attention
// (uniform split-KV chunks, 32x32 swapped-QK in-register softmax, 4 blk/CU,
// setprio) -> out proj (64x128 tile).  B=2 S=2048 H=16 KVH=4 D=64 DIM=1024.
// ---------------------------------------------------------------------------

typedef __bf16 bf16x8 __attribute__((ext_vector_type(8)));
typedef float  f32x4  __attribute__((ext_vector_type(4)));
typedef float  f32x16 __attribute__((ext_vector_type(16)));
typedef int    i32x4  __attribute__((ext_vector_type(4)));

__device__ __forceinline__ unsigned short f2bf(float f) {
  __bf16 h = (__bf16)f;                     // HW RNE cvt
  return __builtin_bit_cast(unsigned short, h);
}

// ---------------- prep: fake-quant all weights + x f32->bf16, one launch ---
__global__ void prep(const float* __restrict__ wq, const float* __restrict__ wk,
                     const float* __restrict__ wv, const float* __restrict__ wp,
                     const float* __restrict__ x,
                     unsigned short* __restrict__ wqkv,
                     unsigned short* __restrict__ wpb,
                     unsigned short* __restrict__ x_bf) {
  int bid = blockIdx.x;
  int t = threadIdx.x;
  if (bid >= 2560) {
    int i = ((bid - 2560) * 256 + t) * 4;
    float4 f = *(const float4*)(x + i);
    ushort4 o;
    o.x = f2bf(f.x); o.y = f2bf(f.y); o.z = f2bf(f.z); o.w = f2bf(f.w);
    *(ushort4*)(x_bf + i) = o;
    return;
  }
  int row = bid;                            // 0..2559
  const float* s;
  unsigned short* d;
  if (row < 1024)      { s = wq + (size_t)row * 1024;          d = wqkv + (size_t)row * 1024; }
  else if (row < 1280) { s = wk + (size_t)(row - 1024) * 1024; d = wqkv + (size_t)row * 1024; }
  else if (row < 1536) { s = wv + (size_t)(row - 1280) * 1024; d = wqkv + (size_t)row * 1024; }
  else                 { s = wp + (size_t)(row - 1536) * 1024; d = wpb + (size_t)(row - 1536) * 1024; }
  float4 v = *(const float4*)(s + t * 4);
  float mx = fmaxf(fmaxf(fabsf(v.x), fabsf(v.y)), fmaxf(fabsf(v.z), fabsf(v.w)));
#pragma unroll
  for (int m = 1; m < 64; m <<= 1) mx = fmaxf(mx, __shfl_xor(mx, m));
  __shared__ float smx[4];
  if ((t & 63) == 0) smx[t >> 6] = mx;
  __syncthreads();
  mx = fmaxf(fmaxf(smx[0], smx[1]), fmaxf(smx[2], smx[3]));
  mx = fmaxf(mx, 1e-8f);
  float scale = mx / 7.0f;                  // exact div to match jnp
  float q0 = fminf(fmaxf(rintf(v.x / scale), -7.0f), 7.0f);
  float q1 = fminf(fmaxf(rintf(v.y / scale), -7.0f), 7.0f);
  float q2 = fminf(fmaxf(rintf(v.z / scale), -7.0f), 7.0f);
  float q3 = fminf(fmaxf(rintf(v.w / scale), -7.0f), 7.0f);
  ushort4 o;
  o.x = f2bf(q0 * scale); o.y = f2bf(q1 * scale);
  o.z = f2bf(q2 * scale); o.w = f2bf(q3 * scale);
  *(ushort4*)(d + t * 4) = o;
}

#define GLDS(g, l)                                                            \
  __builtin_amdgcn_global_load_lds((const __attribute__((address_space(1))) void*)(g), \
                                   (__attribute__((address_space(3))) void*)(l), 16, 0, 0)

// ---------------- proj GEMM: C[M,N] = A[M,K]*B[N,K]^T, 64x128 tile ---------
__global__ __launch_bounds__(512, 2) void gemm_bt64(
    const unsigned short* __restrict__ A, const unsigned short* __restrict__ Bw,
    float* __restrict__ C) {
  const int N = 1024, K = 1024;
  int bidx = blockIdx.x;
  int swz = (bidx & 7) * 64 + (bidx >> 3);    // XCD-chunked swizzle
  int bm = swz >> 3, bn = swz & 7;
  int tid = threadIdx.x, w = tid >> 6, lane = tid & 63;
  int l15 = lane & 15, lh = lane >> 4;
  __shared__ __align__(16) unsigned short ldsA[2][64 * 64];    // 16 KB
  __shared__ __align__(16) unsigned short ldsB[2][128 * 64];   // 32 KB
  int wr = w >> 2, wc = w & 3;
  f32x4 zero = {0.f, 0.f, 0.f, 0.f};
  f32x4 acc[2][2];
#pragma unroll
  for (int i = 0; i < 2; i++)
#pragma unroll
    for (int j = 0; j < 2; j++) acc[i][j] = zero;

  int srow = lane >> 3, schunk = (lane & 7) ^ (lane >> 3);
  const unsigned short* gA0 = A  + (size_t)(bm * 64 + srow) * K + schunk * 8;
  const unsigned short* gB0 = Bw + (size_t)(bn * 128 + srow) * K + schunk * 8;

  GLDS(gA0 + (size_t)(w * 8) * K, (unsigned short*)ldsA[0] + w * 512);
#pragma unroll
  for (int it = 0; it < 2; it++) {
    int seg = w * 2 + it;
    GLDS(gB0 + (size_t)(seg * 8) * K, (unsigned short*)ldsB[0] + seg * 512);
  }
  __syncthreads();
  int cur = 0;
  for (int kt = 0; kt < 16; kt++) {
    if (kt + 1 < 16) {
      int k0 = (kt + 1) * 64;
      GLDS(gA0 + (size_t)(w * 8) * K + k0, (unsigned short*)ldsA[cur ^ 1] + w * 512);
#pragma unroll
      for (int it = 0; it < 2; it++) {
        int seg = w * 2 + it;
        GLDS(gB0 + (size_t)(seg * 8) * K + k0, (unsigned short*)ldsB[cur ^ 1] + seg * 512);
      }
    }
    const unsigned short* cA = ldsA[cur];
    const unsigned short* cB = ldsB[cur];
#pragma unroll
    for (int ks = 0; ks < 2; ks++) {
      bf16x8 af[2], bfr[2];
#pragma unroll
      for (int fm = 0; fm < 2; fm++) {
        int row = wr * 32 + fm * 16 + l15;
        int slot = (ks * 4 + lh) ^ (row & 7);
        af[fm] = *(const bf16x8*)(cA + row * 64 + slot * 8);
      }
#pragma unroll
      for (int fn = 0; fn < 2; fn++) {
        int row = wc * 32 + fn * 16 + l15;
        int slot = (ks * 4 + lh) ^ (row & 7);
        bfr[fn] = *(const bf16x8*)(cB + row * 64 + slot * 8);
      }
#pragma unroll
      for (int fm = 0; fm < 2; fm++)
#pragma unroll
        for (int fn = 0; fn < 2; fn++)
          acc[fm][fn] = __builtin_amdgcn_mfma_f32_16x16x32_bf16(af[fm], bfr[fn], acc[fm][fn], 0, 0, 0);
    }
    __syncthreads();
    cur ^= 1;
  }
#pragma unroll
  for (int fm = 0; fm < 2; fm++) {
    int r0 = bm * 64 + wr * 32 + fm * 16 + lh * 4;
#pragma unroll
    for (int fn = 0; fn < 2; fn++) {
      int c = bn * 128 + wc * 32 + fn * 16 + l15;
#pragma unroll
      for (int reg = 0; reg < 4; reg++)
        C[(size_t)(r0 + reg) * N + c] = acc[fm][fn][reg];
    }
  }
}

// ---------------- QKV GEMM (64x128 tile, 8 waves) --------------------------
// wave (wr=w>>1 in 0..3: 16-row group; wc=w&1: 64-col half == one head).
__global__ __launch_bounds__(512, 4) void gemm_qkv(
    const unsigned short* __restrict__ A, const unsigned short* __restrict__ Bw,
    const float* __restrict__ gainp,
    unsigned short* __restrict__ qb, unsigned short* __restrict__ kbp,
    unsigned short* __restrict__ vbp) {
  const int K = 1024;
  int bidx = blockIdx.x;
  int swz = (bidx & 7) * 96 + (bidx >> 3);    // 768 blocks -> 96/XCD
  int bm = swz / 12, bn = swz % 12;           // bm 0..63, bn 0..11
  int tid = threadIdx.x, w = tid >> 6, lane = tid & 63;
  int l15 = lane & 15, lh = lane >> 4;
  __shared__ __align__(16) unsigned short ldsA[2][64 * 64];    // 16 KB
  __shared__ __align__(16) unsigned short ldsB[2][128 * 64];   // 32 KB
  int wr = w >> 1, wc = w & 1;
  f32x4 zero = {0.f, 0.f, 0.f, 0.f};
  f32x4 acc[4];
#pragma unroll
  for (int j = 0; j < 4; j++) acc[j] = zero;

  int srow = lane >> 3, schunk = (lane & 7) ^ (lane >> 3);
  const unsigned short* gA0 = A  + (size_t)(bm * 64 + srow) * K + schunk * 8;
  const unsigned short* gB0 = Bw + (size_t)(bn * 128 + srow) * K + schunk * 8;

  GLDS(gA0 + (size_t)(w * 8) * K, (unsigned short*)ldsA[0] + w * 512);
#pragma unroll
  for (int it = 0; it < 2; it++) {
    int seg = w * 2 + it;
    GLDS(gB0 + (size_t)(seg * 8) * K, (unsigned short*)ldsB[0] + seg * 512);
  }
  __syncthreads();
  int cur = 0;
  for (int kt = 0; kt < 16; kt++) {
    if (kt + 1 < 16) {
      int k0 = (kt + 1) * 64;
      GLDS(gA0 + (size_t)(w * 8) * K + k0, (unsigned short*)ldsA[cur ^ 1] + w * 512);
#pragma unroll
      for (int it = 0; it < 2; it++) {
        int seg = w * 2 + it;
        GLDS(gB0 + (size_t)(seg * 8) * K + k0, (unsigned short*)ldsB[cur ^ 1] + seg * 512);
      }
    }
    const unsigned short* cA = ldsA[cur];
    const unsigned short* cB = ldsB[cur];
#pragma unroll
    for (int ks = 0; ks < 2; ks++) {
      int rowA = wr * 16 + l15;
      int slotA = (ks * 4 + lh) ^ (rowA & 7);
      bf16x8 af = *(const bf16x8*)(cA + rowA * 64 + slotA * 8);
      bf16x8 bfr[4];
#pragma unroll
      for (int fn = 0; fn < 4; fn++) {
        int row = wc * 64 + fn * 16 + l15;
        int slot = (ks * 4 + lh) ^ (row & 7);
        bfr[fn] = *(const bf16x8*)(cB + row * 64 + slot * 8);
      }
#pragma unroll
      for (int fn = 0; fn < 4; fn++)
        acc[fn] = __builtin_amdgcn_mfma_f32_16x16x32_bf16(af, bfr[fn], acc[fn], 0, 0, 0);
    }
    __syncthreads();
    cur ^= 1;
  }

  // ---- fused epilogue (wave col-half == one head; 16 rows/wave) ----
  int hid = bn * 2 + wc;
  int rbase = bm * 64 + wr * 16;
  if (hid >= 20) {
    int vh = hid - 20;
#pragma unroll
    for (int reg = 0; reg < 4; reg++) {
      int r = rbase + lh * 4 + reg;
      int b = r >> 11, s = r & 2047;
      unsigned short* dst = vbp + (((size_t)(b * 4 + vh) * 2048 + s) << 6);
#pragma unroll
      for (int fn = 0; fn < 4; fn++)
        dst[fn * 16 + l15] = f2bf(acc[fn][reg]);
    }
  } else {
    bool isq = hid < 16;
    float gn = isq ? gainp[hid] : 1.0f;
    float invf0 = __expf(-0.28782313662425572f * (float)l15);         // ln(1e4)/32
    float invf1 = __expf(-0.28782313662425572f * (float)(l15 + 16));
#pragma unroll
    for (int reg = 0; reg < 4; reg++) {
      float y0 = acc[0][reg], y1 = acc[1][reg];
      float y2 = acc[2][reg], y3 = acc[3][reg];
      float ss = y0 * y0 + y1 * y1 + y2 * y2 + y3 * y3;
      ss += __shfl_xor(ss, 1); ss += __shfl_xor(ss, 2);
      ss += __shfl_xor(ss, 4); ss += __shfl_xor(ss, 8);
      float rn = rsqrtf(ss * 0.015625f + 1.1920929e-7f);
      y0 *= rn; y1 *= rn; y2 *= rn; y3 *= rn;
      int r = rbase + lh * 4 + reg;
      int b = r >> 11, s = r & 2047;
      float c0, s0n, c1, s1n;
      __sincosf((float)s * invf0, &s0n, &c0);
      __sincosf((float)s * invf1, &s1n, &c1);
      float o0 = (y0 * c0 + y2 * s0n) * gn;
      float o1 = (y1 * c1 + y3 * s1n) * gn;
      float o2 = (y2 * c0 - y0 * s0n) * gn;
      float o3 = (y3 * c1 - y1 * s1n) * gn;
      unsigned short* dst = isq
        ? qb  + (((size_t)(b * 16 + hid) * 2048 + s) << 6)
        : kbp + (((size_t)(b * 4 + (hid - 16)) * 2048 + s) << 6);
      dst[l15]      = f2bf(o0);
      dst[l15 + 16] = f2bf(o1);
      dst[l15 + 32] = f2bf(o2);
      dst[l15 + 48] = f2bf(o3);
    }
  }
}

// ---------------- V transpose (bf16 in, plain, no permutation) -------------
__global__ void v_transpose(const unsigned short* __restrict__ vbp,
                            unsigned short* __restrict__ vt) {
  int bid = blockIdx.x;          // bk*32 + st
  int st = bid & 31, bk = bid >> 5;
  __shared__ unsigned short tile[64][72];
  int t = threadIdx.x;
  int sl = t >> 2, d0 = (t & 3) * 16;
  const unsigned short* src = vbp + (((size_t)bk * 2048 + st * 64 + sl) << 6) + d0;
  *(ushort4*)&tile[sl][d0]      = *(const ushort4*)(src);
  *(ushort4*)&tile[sl][d0 + 4]  = *(const ushort4*)(src + 4);
  *(ushort4*)&tile[sl][d0 + 8]  = *(const ushort4*)(src + 8);
  *(ushort4*)&tile[sl][d0 + 12] = *(const ushort4*)(src + 12);
  __syncthreads();
  int d = t >> 2, p0 = (t & 3) * 16;
  unsigned short* dst = vt + ((size_t)bk * 64 + d) * 2048 + st * 64 + p0;
#pragma unroll
  for (int jo = 0; jo < 16; jo += 4) {
    ushort4 a;
#pragma unroll
    for (int j = 0; j < 4; j++)
      ((unsigned short*)&a)[j] = tile[p0 + jo + j][d];
    *(ushort4*)(dst + jo) = a;
  }
}

// ---------------- causal flash attention (32x32 swapped-QK, in-reg P) ------
template<bool MASK>
__device__ __forceinline__ void attn_tile(
    int kv0, int q0, int l31, int hi, float M2,
    const unsigned short* ldsK, const unsigned short* ldsV,
    const bf16x8 (&qf)[4], float& lsum, f32x16 (&o)[2]) {
  const float K2 = 0.18033688011112042f;  // 0.125 * log2(e)
  f32x16 sc[2];
#pragma unroll
  for (int i = 0; i < 16; i++) { sc[0][i] = 0.f; sc[1][i] = 0.f; }
  // --- QK^T swapped: A=K (rows=kv), B=Q (cols=q) ---
  __builtin_amdgcn_s_setprio(1);
#pragma unroll
  for (int ks = 0; ks < 4; ks++) {
    int slot0 = (2 * ks + hi) ^ (l31 & 7);
    bf16x8 kf0 = *(const bf16x8*)(ldsK + l31 * 64 + slot0 * 8);
    int row1 = 32 + l31;
    int slot1 = (2 * ks + hi) ^ (row1 & 7);
    bf16x8 kf1 = *(const bf16x8*)(ldsK + row1 * 64 + slot1 * 8);
    sc[0] = __builtin_amdgcn_mfma_f32_32x32x16_bf16(kf0, qf[ks], sc[0], 0, 0, 0);
    sc[1] = __builtin_amdgcn_mfma_f32_32x32x16_bf16(kf1, qf[ks], sc[1], 0, 0, 0);
  }
  __builtin_amdgcn_s_setprio(0);
  // --- per-fn: softmax quarter then its PV pair (overlap VALU with MFMA) ---
  float ls = 0.f;
  int rowq = q0 + l31;
#pragma unroll
  for (int fn = 0; fn < 2; fn++) {
    unsigned int Wp[4][2];
#pragma unroll
    for (int g = 0; g < 4; g++) {
      float p4[4];
#pragma unroll
      for (int m = 0; m < 4; m++) {
        int r = 4 * g + m;
        float s = __builtin_fmaf(sc[fn][r], K2, -M2);
        if (MASK) {
          int col = kv0 + fn * 32 + m + 8 * g + 4 * hi;  // crow(r,hi)
          if (col > rowq) s = -1e30f;
        }
        float p = __builtin_amdgcn_exp2f(s);
        ls += p;
        p4[m] = p;
      }
      asm("v_cvt_pk_bf16_f32 %0, %1, %2" : "=v"(Wp[g][0]) : "v"(p4[0]), "v"(p4[1]));
      asm("v_cvt_pk_bf16_f32 %0, %1, %2" : "=v"(Wp[g][1]) : "v"(p4[2]), "v"(p4[3]));
    }
    __builtin_amdgcn_s_setprio(1);
#pragma unroll
    for (int e = 0; e < 2; e++) {
      int ksg = fn * 2 + e;
      unsigned int u0 = Wp[2 * e][0], u1 = Wp[2 * e + 1][0];
      unsigned int u2 = Wp[2 * e][1], u3 = Wp[2 * e + 1][1];
      asm("v_permlane32_swap_b32 %0, %1" : "+v"(u0), "+v"(u1));
      asm("v_permlane32_swap_b32 %0, %1" : "+v"(u2), "+v"(u3));
      i32x4 pw;
      pw[0] = (int)u0; pw[1] = (int)u2; pw[2] = (int)u1; pw[3] = (int)u3;
      bf16x8 pf = __builtin_bit_cast(bf16x8, pw);
      int slot0 = (2 * ksg + hi) ^ (l31 & 7);
      bf16x8 v0 = *(const bf16x8*)(ldsV + l31 * 64 + slot0 * 8);
      int row1 = 32 + l31;
      int slot1 = (2 * ksg + hi) ^ (row1 & 7);
      bf16x8 v1 = *(const bf16x8*)(ldsV + row1 * 64 + slot1 * 8);
      o[0] = __builtin_amdgcn_mfma_f32_32x32x16_bf16(pf, v0, o[0], 0, 0, 0);
      o[1] = __builtin_amdgcn_mfma_f32_32x32x16_bf16(pf, v1, o[1], 0, 0, 0);
    }
    __builtin_amdgcn_s_setprio(0);
  }
  lsum += ls;
}

__global__ __launch_bounds__(256, 4) void attn_fwd(
    const unsigned short* __restrict__ qbuf, const unsigned short* __restrict__ kb,
    const unsigned short* __restrict__ vtb, const float* __restrict__ gain,
    unsigned short* __restrict__ ob, unsigned short* __restrict__ pO,
    float* __restrict__ pL) {
  int bid = blockIdx.x;
  int cid = 71 - (bid >> 5);      // heavy chunks dispatch first
  int bh = bid & 31;
  int b = bh >> 4, h = bh & 15;
  int qb = 0, cum = 0;
  for (int q = 0; q < 16; q++) {
    int ncq = (2 * q + 5) >> 2;
    if (cid < cum + ncq) { qb = q; break; }
    cum += ncq;
  }
  int nt = 2 * qb + 2;
  int nc = (2 * qb + 5) >> 2;
  int ch = cid - cum;
  int base = nt / nc, rem = nt % nc;
  int t0 = ch * base + (ch < rem ? ch : rem);
  int t1 = t0 + base + (ch < rem ? 1 : 0);
  bool direct = (nc == 1);        // qb 0,1

  int tid = threadIdx.x;
  int w = tid >> 6, lane = tid & 63;
  int l31 = lane & 31, hi = lane >> 5;
  int q0 = qb * 128 + w * 32;
  int kvh = h >> 2;
  const unsigned short* Q  = qbuf + (size_t)(b * 16 + h) * (2048 * 64);
  const unsigned short* Kg = kb   + (size_t)(b * 4 + kvh) * (2048 * 64);
  const unsigned short* Vg = vtb  + (size_t)(b * 4 + kvh) * (64 * 2048);

  __shared__ __align__(16) unsigned short ldsK[2][64 * 64];    // 16 KB
  __shared__ __align__(16) unsigned short ldsV[2][64 * 64];    // 16 KB

  float gn = gain[h];
  float M2 = __builtin_fmaf(fabsf(gn), 1.46f, 0.02f);  // static max bound

  // Q as B-frags: col=l31 (q row), k = 16ks + 8hi + j
  bf16x8 qf[4];
#pragma unroll
  for (int ks = 0; ks < 4; ks++)
    qf[ks] = *(const bf16x8*)(Q + (size_t)(q0 + l31) * 64 + ks * 16 + hi * 8);

  f32x16 o[2];
#pragma unroll
  for (int i = 0; i < 16; i++) { o[0][i] = 0.f; o[1][i] = 0.f; }
  float lsum = 0.f;

  int srow = lane >> 3;
  int schunk = (lane & 7) ^ (lane >> 3);
  int full = q0 >> 6;

#pragma unroll
  for (int it = 0; it < 2; it++) {
    int seg = w * 2 + it;
    GLDS(Kg + (size_t)(t0 * 64 + seg * 8 + srow) * 64 + schunk * 8,
         (unsigned short*)ldsK[0] + seg * 512);
    GLDS(Vg + (size_t)(seg * 8 + srow) * 2048 + t0 * 64 + schunk * 8,
         (unsigned short*)ldsV[0] + seg * 512);
  }
  __syncthreads();
  int cur = 0;
  for (int t = t0; t < t1; t++) {
    int kv0 = t * 64;
    if (t + 1 < t1) {
      int kn = kv0 + 64;
#pragma unroll
      for (int it = 0; it < 2; it++) {
        int seg = w * 2 + it;
        GLDS(Kg + (size_t)(kn + seg * 8 + srow) * 64 + schunk * 8,
             (unsigned short*)ldsK[cur ^ 1] + seg * 512);
        GLDS(Vg + (size_t)(seg * 8 + srow) * 2048 + kn + schunk * 8,
             (unsigned short*)ldsV[cur ^ 1] + seg * 512);
      }
    }
    if (t < full)
      attn_tile<false>(kv0, q0, l31, hi, M2, ldsK[cur], ldsV[cur], qf, lsum, o);
    else if (kv0 <= q0 + 31)
      attn_tile<true>(kv0, q0, l31, hi, M2, ldsK[cur], ldsV[cur], qf, lsum, o);
    __syncthreads();
    cur ^= 1;
  }

  float lred = lsum + __shfl_xor(lsum, 32);   // full row sum (q = l31)
  if (direct) {
    float linv = 1.0f / lred;
#pragma unroll
    for (int r = 0; r < 16; r++) {
      int qr = (r & 3) + 8 * (r >> 2) + 4 * hi;     // q row within 32
      float iv = __shfl(linv, qr);
      size_t rb = (size_t)(b * 2048 + q0 + qr) * 1024 + h * 64;
      ob[rb + l31]      = f2bf(o[0][r] * iv);
      ob[rb + 32 + l31] = f2bf(o[1][r] * iv);
    }
  } else {
    int slot = bh * 70 + (cid - 2);
    unsigned short* po = pO + ((size_t)slot << 13);   // 128*64 bf16, plain
    float* pl = pL + slot * 128;
    if (lane < 32) pl[w * 32 + l31] = lred;
#pragma unroll
    for (int r = 0; r < 16; r++) {
      int qr = (r & 3) + 8 * (r >> 2) + 4 * hi;
      int row = w * 32 + qr;
      po[row * 64 + l31]      = f2bf(o[0][r]);
      po[row * 64 + 32 + l31] = f2bf(o[1][r]);
    }
  }
}

// ---------------- finalize: sum chunk partials, normalize, write bf16 ------
__global__ __launch_bounds__(128) void attn_finalize(
    const unsigned short* __restrict__ pO, const float* __restrict__ pL,
    unsigned short* __restrict__ ob) {
  int bid = blockIdx.x;           // 448 = 32 bh * 14 qb(2..15)
  int qb = 2 + bid % 14;
  int bh = bid / 14;
  int b = bh >> 4, h = bh & 15;
  int cum = 0;
  for (int q = 0; q < 16; q++) {
    if (q == qb) break;
    cum += (2 * q + 5) >> 2;
  }
  int nc = (2 * qb + 5) >> 2;
  int s0 = bh * 70 + (cum - 2);

  int row = threadIdx.x;          // 128 rows
  float acc[64];
#pragma unroll
  for (int j = 0; j < 64; j++) acc[j] = 0.f;
  float l = 0.f;
  for (int c = 0; c < nc; c++) {
    const unsigned short* po = pO + (((size_t)(s0 + c)) << 13) + row * 64;
    l += pL[(s0 + c) * 128 + row];
#pragma unroll
    for (int j = 0; j < 8; j++) {
      uint4 u = *(const uint4*)(po + j * 8);
      const unsigned short* us = (const unsigned short*)&u;
#pragma unroll
      for (int e = 0; e < 8; e++) {
        unsigned int bits = (unsigned int)us[e] << 16;
        acc[j * 8 + e] += __builtin_bit_cast(float, bits);
      }
    }
  }
  float inv = 1.0f / l;
  unsigned short* dst = ob + (size_t)(b * 2048 + qb * 128 + row) * 1024 + h * 64;
  unsigned short outv[64];
#pragma unroll
  for (int c = 0; c < 64; c++) outv[c] = f2bf(acc[c] * inv);
#pragma unroll
  for (int j = 0; j < 8; j++)
    *(uint4*)(dst + j * 8) = *(const uint4*)(outv + j * 8);
}

// ---------------------------------------------------------------------------
extern "C" void kernel_launch(void* const* d_in, const int* in_sizes, int n_in,
                              void* d_out, int out_size, void* d_ws, size_t ws_size,
                              hipStream_t stream) {
  const float* x    = (const float*)d_in[0];
  const float* w_q  = (const float*)d_in[1];
  const float* w_k  = (const float*)d_in[2];
  const float* w_v  = (const float*)d_in[3];
  const float* w_p  = (const float*)d_in[4];
  const float* gain = (const float*)d_in[5];
  float* out = (float*)d_out;

  char* ws = (char*)d_ws;
  unsigned short* x_bf  = (unsigned short*)ws;                   //  8 MB
  unsigned short* wqkv  = (unsigned short*)(ws + (8u << 20));    //  3 MB
  unsigned short* wp    = (unsigned short*)(ws + (11u << 20));   //  2 MB
  unsigned short* qbuf  = (unsigned short*)(ws + (13u << 20));   //  8 MB
  unsigned short* kbuf  = (unsigned short*)(ws + (21u << 20));   //  2 MB
  unsigned short* vbuf  = (unsigned short*)(ws + (23u << 20));   //  2 MB
  unsigned short* vtbuf = (unsigned short*)(ws + (25u << 20));   //  2 MB
  unsigned short* aout  = (unsigned short*)(ws + (27u << 20));   //  8 MB
  unsigned short* pO    = (unsigned short*)(ws + (35u << 20));   // 37 MB
  float*          pL    = (float*)(ws + (73u << 20));            //  2 MB

  prep<<<6656, 256, 0, stream>>>(w_q, w_k, w_v, w_p, x, wqkv, wp, x_bf);
  gemm_qkv<<<768, 512, 0, stream>>>(x_bf, wqkv, gain, qbuf, kbuf, vbuf);
  v_transpose<<<256, 256, 0, stream>>>(vbuf, vtbuf);
  attn_fwd<<<2304, 256, 0, stream>>>(qbuf, kbuf, vtbuf, gain, aout, pO, pL);
  attn_finalize<<<448, 128, 0, stream>>>(pO, pL, aout);
  gemm_bt64<<<512, 512, 0, stream>>>(aout, wp, out);
}

// Round 23
// 95.599 us; speedup vs baseline: 1.0264x; 1.0264x over previous
//
#include <hip/hip_runtime.h>

// ---------------------------------------------------------------------------
// CausalSelfAttention: fake-quant-i4 weights -> QKV gemm (64x128 tile, fused
// RMSNorm+RoPE+gain epilogue + fused V-transpose) -> GQA causal flash
// attention (uniform split-KV chunks, 32x32 swapped-QK in-register softmax,
// 4 blk/CU, setprio) -> out proj (64x128 tile).  B=2 S=2048 H=16 KVH=4 D=64.
// ---------------------------------------------------------------------------

typedef __bf16 bf16x8 __attribute__((ext_vector_type(8)));
typedef float  f32x4  __attribute__((ext_vector_type(4)));
typedef float  f32x16 __attribute__((ext_vector_type(16)));
typedef int    i32x4  __attribute__((ext_vector_type(4)));

__device__ __forceinline__ unsigned short f2bf(float f) {
  __bf16 h = (__bf16)f;                     // HW RNE cvt
  return __builtin_bit_cast(unsigned short, h);
}

// ---------------- prep: fake-quant all weights + x f32->bf16, one launch ---
__global__ void prep(const float* __restrict__ wq, const float* __restrict__ wk,
                     const float* __restrict__ wv, const float* __restrict__ wp,
                     const float* __restrict__ x,
                     unsigned short* __restrict__ wqkv,
                     unsigned short* __restrict__ wpb,
                     unsigned short* __restrict__ x_bf) {
  int bid = blockIdx.x;
  int t = threadIdx.x;
  if (bid >= 2560) {
    int i = ((bid - 2560) * 256 + t) * 4;
    float4 f = *(const float4*)(x + i);
    ushort4 o;
    o.x = f2bf(f.x); o.y = f2bf(f.y); o.z = f2bf(f.z); o.w = f2bf(f.w);
    *(ushort4*)(x_bf + i) = o;
    return;
  }
  int row = bid;                            // 0..2559
  const float* s;
  unsigned short* d;
  if (row < 1024)      { s = wq + (size_t)row * 1024;          d = wqkv + (size_t)row * 1024; }
  else if (row < 1280) { s = wk + (size_t)(row - 1024) * 1024; d = wqkv + (size_t)row * 1024; }
  else if (row < 1536) { s = wv + (size_t)(row - 1280) * 1024; d = wqkv + (size_t)row * 1024; }
  else                 { s = wp + (size_t)(row - 1536) * 1024; d = wpb + (size_t)(row - 1536) * 1024; }
  float4 v = *(const float4*)(s + t * 4);
  float mx = fmaxf(fmaxf(fabsf(v.x), fabsf(v.y)), fmaxf(fabsf(v.z), fabsf(v.w)));
#pragma unroll
  for (int m = 1; m < 64; m <<= 1) mx = fmaxf(mx, __shfl_xor(mx, m));
  __shared__ float smx[4];
  if ((t & 63) == 0) smx[t >> 6] = mx;
  __syncthreads();
  mx = fmaxf(fmaxf(smx[0], smx[1]), fmaxf(smx[2], smx[3]));
  mx = fmaxf(mx, 1e-8f);
  float scale = mx / 7.0f;                  // exact div to match jnp
  float q0 = fminf(fmaxf(rintf(v.x / scale), -7.0f), 7.0f);
  float q1 = fminf(fmaxf(rintf(v.y / scale), -7.0f), 7.0f);
  float q2 = fminf(fmaxf(rintf(v.z / scale), -7.0f), 7.0f);
  float q3 = fminf(fmaxf(rintf(v.w / scale), -7.0f), 7.0f);
  ushort4 o;
  o.x = f2bf(q0 * scale); o.y = f2bf(q1 * scale);
  o.z = f2bf(q2 * scale); o.w = f2bf(q3 * scale);
  *(ushort4*)(d + t * 4) = o;
}

#define GLDS(g, l)                                                            \
  __builtin_amdgcn_global_load_lds((const __attribute__((address_space(1))) void*)(g), \
                                   (__attribute__((address_space(3))) void*)(l), 16, 0, 0)

// ---------------- proj GEMM: C[M,N] = A[M,K]*B[N,K]^T, 64x128 tile ---------
__global__ __launch_bounds__(512, 2) void gemm_bt64(
    const unsigned short* __restrict__ A, const unsigned short* __restrict__ Bw,
    float* __restrict__ C) {
  const int N = 1024, K = 1024;
  int bidx = blockIdx.x;
  int swz = (bidx & 7) * 64 + (bidx >> 3);    // XCD-chunked swizzle
  int bm = swz >> 3, bn = swz & 7;
  int tid = threadIdx.x, w = tid >> 6, lane = tid & 63;
  int l15 = lane & 15, lh = lane >> 4;
  __shared__ __align__(16) unsigned short ldsA[2][64 * 64];    // 16 KB
  __shared__ __align__(16) unsigned short ldsB[2][128 * 64];   // 32 KB
  int wr = w >> 2, wc = w & 3;
  f32x4 zero = {0.f, 0.f, 0.f, 0.f};
  f32x4 acc[2][2];
#pragma unroll
  for (int i = 0; i < 2; i++)
#pragma unroll
    for (int j = 0; j < 2; j++) acc[i][j] = zero;

  int srow = lane >> 3, schunk = (lane & 7) ^ (lane >> 3);
  const unsigned short* gA0 = A  + (size_t)(bm * 64 + srow) * K + schunk * 8;
  const unsigned short* gB0 = Bw + (size_t)(bn * 128 + srow) * K + schunk * 8;

  GLDS(gA0 + (size_t)(w * 8) * K, (unsigned short*)ldsA[0] + w * 512);
#pragma unroll
  for (int it = 0; it < 2; it++) {
    int seg = w * 2 + it;
    GLDS(gB0 + (size_t)(seg * 8) * K, (unsigned short*)ldsB[0] + seg * 512);
  }
  __syncthreads();
  int cur = 0;
  for (int kt = 0; kt < 16; kt++) {
    if (kt + 1 < 16) {
      int k0 = (kt + 1) * 64;
      GLDS(gA0 + (size_t)(w * 8) * K + k0, (unsigned short*)ldsA[cur ^ 1] + w * 512);
#pragma unroll
      for (int it = 0; it < 2; it++) {
        int seg = w * 2 + it;
        GLDS(gB0 + (size_t)(seg * 8) * K + k0, (unsigned short*)ldsB[cur ^ 1] + seg * 512);
      }
    }
    const unsigned short* cA = ldsA[cur];
    const unsigned short* cB = ldsB[cur];
#pragma unroll
    for (int ks = 0; ks < 2; ks++) {
      bf16x8 af[2], bfr[2];
#pragma unroll
      for (int fm = 0; fm < 2; fm++) {
        int row = wr * 32 + fm * 16 + l15;
        int slot = (ks * 4 + lh) ^ (row & 7);
        af[fm] = *(const bf16x8*)(cA + row * 64 + slot * 8);
      }
#pragma unroll
      for (int fn = 0; fn < 2; fn++) {
        int row = wc * 32 + fn * 16 + l15;
        int slot = (ks * 4 + lh) ^ (row & 7);
        bfr[fn] = *(const bf16x8*)(cB + row * 64 + slot * 8);
      }
#pragma unroll
      for (int fm = 0; fm < 2; fm++)
#pragma unroll
        for (int fn = 0; fn < 2; fn++)
          acc[fm][fn] = __builtin_amdgcn_mfma_f32_16x16x32_bf16(af[fm], bfr[fn], acc[fm][fn], 0, 0, 0);
    }
    __syncthreads();
    cur ^= 1;
  }
#pragma unroll
  for (int fm = 0; fm < 2; fm++) {
    int r0 = bm * 64 + wr * 32 + fm * 16 + lh * 4;
#pragma unroll
    for (int fn = 0; fn < 2; fn++) {
      int c = bn * 128 + wc * 32 + fn * 16 + l15;
#pragma unroll
      for (int reg = 0; reg < 4; reg++)
        C[(size_t)(r0 + reg) * N + c] = acc[fm][fn][reg];
    }
  }
}

// ---------------- QKV GEMM (64x128 tile, 8 waves) + fused V-transpose ------
// wave (wr=w>>1 in 0..3: 16-row group; wc=w&1: 64-col half == one head).
// Blocks with bn>=10 hold only V heads: transpose in LDS, write vt directly.
__global__ __launch_bounds__(512, 4) void gemm_qkv(
    const unsigned short* __restrict__ A, const unsigned short* __restrict__ Bw,
    const float* __restrict__ gainp,
    unsigned short* __restrict__ qb, unsigned short* __restrict__ kbp,
    unsigned short* __restrict__ vt) {
  const int K = 1024;
  int bidx = blockIdx.x;
  int swz = (bidx & 7) * 96 + (bidx >> 3);    // 768 blocks -> 96/XCD
  int bm = swz / 12, bn = swz % 12;           // bm 0..63, bn 0..11
  int tid = threadIdx.x, w = tid >> 6, lane = tid & 63;
  int l15 = lane & 15, lh = lane >> 4;
  __shared__ __align__(16) unsigned short ldsA[2][64 * 64];    // 16 KB
  __shared__ __align__(16) unsigned short ldsB[2][128 * 64];   // 32 KB
  int wr = w >> 1, wc = w & 1;
  f32x4 zero = {0.f, 0.f, 0.f, 0.f};
  f32x4 acc[4];
#pragma unroll
  for (int j = 0; j < 4; j++) acc[j] = zero;

  int srow = lane >> 3, schunk = (lane & 7) ^ (lane >> 3);
  const unsigned short* gA0 = A  + (size_t)(bm * 64 + srow) * K + schunk * 8;
  const unsigned short* gB0 = Bw + (size_t)(bn * 128 + srow) * K + schunk * 8;

  GLDS(gA0 + (size_t)(w * 8) * K, (unsigned short*)ldsA[0] + w * 512);
#pragma unroll
  for (int it = 0; it < 2; it++) {
    int seg = w * 2 + it;
    GLDS(gB0 + (size_t)(seg * 8) * K, (unsigned short*)ldsB[0] + seg * 512);
  }
  __syncthreads();
  int cur = 0;
  for (int kt = 0; kt < 16; kt++) {
    if (kt + 1 < 16) {
      int k0 = (kt + 1) * 64;
      GLDS(gA0 + (size_t)(w * 8) * K + k0, (unsigned short*)ldsA[cur ^ 1] + w * 512);
#pragma unroll
      for (int it = 0; it < 2; it++) {
        int seg = w * 2 + it;
        GLDS(gB0 + (size_t)(seg * 8) * K + k0, (unsigned short*)ldsB[cur ^ 1] + seg * 512);
      }
    }
    const unsigned short* cA = ldsA[cur];
    const unsigned short* cB = ldsB[cur];
#pragma unroll
    for (int ks = 0; ks < 2; ks++) {
      int rowA = wr * 16 + l15;
      int slotA = (ks * 4 + lh) ^ (rowA & 7);
      bf16x8 af = *(const bf16x8*)(cA + rowA * 64 + slotA * 8);
      bf16x8 bfr[4];
#pragma unroll
      for (int fn = 0; fn < 4; fn++) {
        int row = wc * 64 + fn * 16 + l15;
        int slot = (ks * 4 + lh) ^ (row & 7);
        bfr[fn] = *(const bf16x8*)(cB + row * 64 + slot * 8);
      }
#pragma unroll
      for (int fn = 0; fn < 4; fn++)
        acc[fn] = __builtin_amdgcn_mfma_f32_16x16x32_bf16(af, bfr[fn], acc[fn], 0, 0, 0);
    }
    __syncthreads();
    cur ^= 1;
  }

  // ---- fused epilogue ----
  int hid = bn * 2 + wc;
  int rbase = bm * 64 + wr * 16;
  if (bn >= 10) {
    // whole block is V heads (hid 20..23): LDS transpose, write vt [d][s]
    unsigned short* ldsT = (unsigned short*)ldsB;   // 128*68 shorts = 17 KB
    __syncthreads();                                 // main-loop LDS reads done
#pragma unroll
    for (int reg = 0; reg < 4; reg++) {
      int sl = wr * 16 + lh * 4 + reg;               // 0..63 (local row)
#pragma unroll
      for (int fn = 0; fn < 4; fn++) {
        int db = wc * 64 + fn * 16 + l15;            // 0..127 (head-pair col)
        ldsT[db * 68 + sl] = f2bf(acc[fn][reg]);
      }
    }
    __syncthreads();
    int db = tid >> 2;                               // 0..127
    int sseg = (tid & 3) * 16;                       // 0,16,32,48
    int vh = (bn - 10) * 2 + (db >> 6);              // 0..3
    int d = db & 63;
    int gr = bm * 64 + sseg;
    int bb = gr >> 11, sgl = gr & 2047;
    unsigned short* dst = vt + ((size_t)(bb * 4 + vh) * 64 + d) * 2048 + sgl;
#pragma unroll
    for (int j = 0; j < 16; j += 4)
      *(ushort4*)(dst + j) = *(const ushort4*)(ldsT + db * 68 + sseg + j);
  } else {
    bool isq = hid < 16;
    float gn = isq ? gainp[hid] : 1.0f;
    float invf0 = __expf(-0.28782313662425572f * (float)l15);         // ln(1e4)/32
    float invf1 = __expf(-0.28782313662425572f * (float)(l15 + 16));
#pragma unroll
    for (int reg = 0; reg < 4; reg++) {
      float y0 = acc[0][reg], y1 = acc[1][reg];
      float y2 = acc[2][reg], y3 = acc[3][reg];
      float ss = y0 * y0 + y1 * y1 + y2 * y2 + y3 * y3;
      ss += __shfl_xor(ss, 1); ss += __shfl_xor(ss, 2);
      ss += __shfl_xor(ss, 4); ss += __shfl_xor(ss, 8);
      float rn = rsqrtf(ss * 0.015625f + 1.1920929e-7f);
      y0 *= rn; y1 *= rn; y2 *= rn; y3 *= rn;
      int r = rbase + lh * 4 + reg;
      int b = r >> 11, s = r & 2047;
      float c0, s0n, c1, s1n;
      __sincosf((float)s * invf0, &s0n, &c0);
      __sincosf((float)s * invf1, &s1n, &c1);
      float o0 = (y0 * c0 + y2 * s0n) * gn;
      float o1 = (y1 * c1 + y3 * s1n) * gn;
      float o2 = (y2 * c0 - y0 * s0n) * gn;
      float o3 = (y3 * c1 - y1 * s1n) * gn;
      unsigned short* dst = isq
        ? qb  + (((size_t)(b * 16 + hid) * 2048 + s) << 6)
        : kbp + (((size_t)(b * 4 + (hid - 16)) * 2048 + s) << 6);
      dst[l15]      = f2bf(o0);
      dst[l15 + 16] = f2bf(o1);
      dst[l15 + 32] = f2bf(o2);
      dst[l15 + 48] = f2bf(o3);
    }
  }
}

// ---------------- causal flash attention (32x32 swapped-QK, in-reg P) ------
template<bool MASK>
__device__ __forceinline__ void attn_tile(
    int kv0, int q0, int l31, int hi, float M2,
    const unsigned short* ldsK, const unsigned short* ldsV,
    const bf16x8 (&qf)[4], float& lsum, f32x16 (&o)[2]) {
  const float K2 = 0.18033688011112042f;  // 0.125 * log2(e)
  f32x16 sc[2];
#pragma unroll
  for (int i = 0; i < 16; i++) { sc[0][i] = 0.f; sc[1][i] = 0.f; }
  // --- QK^T swapped: A=K (rows=kv), B=Q (cols=q) ---
  __builtin_amdgcn_s_setprio(1);
#pragma unroll
  for (int ks = 0; ks < 4; ks++) {
    int slot0 = (2 * ks + hi) ^ (l31 & 7);
    bf16x8 kf0 = *(const bf16x8*)(ldsK + l31 * 64 + slot0 * 8);
    int row1 = 32 + l31;
    int slot1 = (2 * ks + hi) ^ (row1 & 7);
    bf16x8 kf1 = *(const bf16x8*)(ldsK + row1 * 64 + slot1 * 8);
    sc[0] = __builtin_amdgcn_mfma_f32_32x32x16_bf16(kf0, qf[ks], sc[0], 0, 0, 0);
    sc[1] = __builtin_amdgcn_mfma_f32_32x32x16_bf16(kf1, qf[ks], sc[1], 0, 0, 0);
  }
  __builtin_amdgcn_s_setprio(0);
  // --- per-fn: softmax quarter then its PV pair (overlap VALU with MFMA) ---
  float ls = 0.f;
  int rowq = q0 + l31;
#pragma unroll
  for (int fn = 0; fn < 2; fn++) {
    unsigned int Wp[4][2];
#pragma unroll
    for (int g = 0; g < 4; g++) {
      float p4[4];
#pragma unroll
      for (int m = 0; m < 4; m++) {
        int r = 4 * g + m;
        float s = __builtin_fmaf(sc[fn][r], K2, -M2);
        if (MASK) {
          int col = kv0 + fn * 32 + m + 8 * g + 4 * hi;  // crow(r,hi)
          if (col > rowq) s = -1e30f;
        }
        float p = __builtin_amdgcn_exp2f(s);
        ls += p;
        p4[m] = p;
      }
      asm("v_cvt_pk_bf16_f32 %0, %1, %2" : "=v"(Wp[g][0]) : "v"(p4[0]), "v"(p4[1]));
      asm("v_cvt_pk_bf16_f32 %0, %1, %2" : "=v"(Wp[g][1]) : "v"(p4[2]), "v"(p4[3]));
    }
    __builtin_amdgcn_s_setprio(1);
#pragma unroll
    for (int e = 0; e < 2; e++) {
      int ksg = fn * 2 + e;
      unsigned int u0 = Wp[2 * e][0], u1 = Wp[2 * e + 1][0];
      unsigned int u2 = Wp[2 * e][1], u3 = Wp[2 * e + 1][1];
      asm("v_permlane32_swap_b32 %0, %1" : "+v"(u0), "+v"(u1));
      asm("v_permlane32_swap_b32 %0, %1" : "+v"(u2), "+v"(u3));
      i32x4 pw;
      pw[0] = (int)u0; pw[1] = (int)u2; pw[2] = (int)u1; pw[3] = (int)u3;
      bf16x8 pf = __builtin_bit_cast(bf16x8, pw);
      int slot0 = (2 * ksg + hi) ^ (l31 & 7);
      bf16x8 v0 = *(const bf16x8*)(ldsV + l31 * 64 + slot0 * 8);
      int row1 = 32 + l31;
      int slot1 = (2 * ksg + hi) ^ (row1 & 7);
      bf16x8 v1 = *(const bf16x8*)(ldsV + row1 * 64 + slot1 * 8);
      o[0] = __builtin_amdgcn_mfma_f32_32x32x16_bf16(pf, v0, o[0], 0, 0, 0);
      o[1] = __builtin_amdgcn_mfma_f32_32x32x16_bf16(pf, v1, o[1], 0, 0, 0);
    }
    __builtin_amdgcn_s_setprio(0);
  }
  lsum += ls;
}

__global__ __launch_bounds__(256, 4) void attn_fwd(
    const unsigned short* __restrict__ qbuf, const unsigned short* __restrict__ kb,
    const unsigned short* __restrict__ vtb, const float* __restrict__ gain,
    unsigned short* __restrict__ ob, unsigned short* __restrict__ pO,
    float* __restrict__ pL) {
  int bid = blockIdx.x;
  int cid = 71 - (bid >> 5);      // heavy chunks dispatch first
  int bh = bid & 31;
  int b = bh >> 4, h = bh & 15;
  int qb = 0, cum = 0;
  for (int q = 0; q < 16; q++) {
    int ncq = (2 * q + 5) >> 2;
    if (cid < cum + ncq) { qb = q; break; }
    cum += ncq;
  }
  int nt = 2 * qb + 2;
  int nc = (2 * qb + 5) >> 2;
  int ch = cid - cum;
  int base = nt / nc, rem = nt % nc;
  int t0 = ch * base + (ch < rem ? ch : rem);
  int t1 = t0 + base + (ch < rem ? 1 : 0);
  bool direct = (nc == 1);        // qb 0,1

  int tid = threadIdx.x;
  int w = tid >> 6, lane = tid & 63;
  int l31 = lane & 31, hi = lane >> 5;
  int q0 = qb * 128 + w * 32;
  int kvh = h >> 2;
  const unsigned short* Q  = qbuf + (size_t)(b * 16 + h) * (2048 * 64);
  const unsigned short* Kg = kb   + (size_t)(b * 4 + kvh) * (2048 * 64);
  const unsigned short* Vg = vtb  + (size_t)(b * 4 + kvh) * (64 * 2048);

  __shared__ __align__(16) unsigned short ldsK[2][64 * 64];    // 16 KB
  __shared__ __align__(16) unsigned short ldsV[2][64 * 64];    // 16 KB

  float gn = gain[h];
  float M2 = __builtin_fmaf(fabsf(gn), 1.46f, 0.02f);  // static max bound

  // Q as B-frags: col=l31 (q row), k = 16ks + 8hi + j
  bf16x8 qf[4];
#pragma unroll
  for (int ks = 0; ks < 4; ks++)
    qf[ks] = *(const bf16x8*)(Q + (size_t)(q0 + l31) * 64 + ks * 16 + hi * 8);

  f32x16 o[2];
#pragma unroll
  for (int i = 0; i < 16; i++) { o[0][i] = 0.f; o[1][i] = 0.f; }
  float lsum = 0.f;

  int srow = lane >> 3;
  int schunk = (lane & 7) ^ (lane >> 3);
  int full = q0 >> 6;

#pragma unroll
  for (int it = 0; it < 2; it++) {
    int seg = w * 2 + it;
    GLDS(Kg + (size_t)(t0 * 64 + seg * 8 + srow) * 64 + schunk * 8,
         (unsigned short*)ldsK[0] + seg * 512);
    GLDS(Vg + (size_t)(seg * 8 + srow) * 2048 + t0 * 64 + schunk * 8,
         (unsigned short*)ldsV[0] + seg * 512);
  }
  __syncthreads();
  int cur = 0;
  for (int t = t0; t < t1; t++) {
    int kv0 = t * 64;
    if (t + 1 < t1) {
      int kn = kv0 + 64;
#pragma unroll
      for (int it = 0; it < 2; it++) {
        int seg = w * 2 + it;
        GLDS(Kg + (size_t)(kn + seg * 8 + srow) * 64 + schunk * 8,
             (unsigned short*)ldsK[cur ^ 1] + seg * 512);
        GLDS(Vg + (size_t)(seg * 8 + srow) * 2048 + kn + schunk * 8,
             (unsigned short*)ldsV[cur ^ 1] + seg * 512);
      }
    }
    if (t < full)
      attn_tile<false>(kv0, q0, l31, hi, M2, ldsK[cur], ldsV[cur], qf, lsum, o);
    else if (kv0 <= q0 + 31)
      attn_tile<true>(kv0, q0, l31, hi, M2, ldsK[cur], ldsV[cur], qf, lsum, o);
    __syncthreads();
    cur ^= 1;
  }

  float lred = lsum + __shfl_xor(lsum, 32);   // full row sum (q = l31)
  if (direct) {
    float linv = 1.0f / lred;
#pragma unroll
    for (int r = 0; r < 16; r++) {
      int qr = (r & 3) + 8 * (r >> 2) + 4 * hi;     // q row within 32
      float iv = __shfl(linv, qr);
      size_t rb = (size_t)(b * 2048 + q0 + qr) * 1024 + h * 64;
      ob[rb + l31]      = f2bf(o[0][r] * iv);
      ob[rb + 32 + l31] = f2bf(o[1][r] * iv);
    }
  } else {
    int slot = bh * 70 + (cid - 2);
    unsigned short* po = pO + ((size_t)slot << 13);   // 128*64 bf16, plain
    float* pl = pL + slot * 128;
    if (lane < 32) pl[w * 32 + l31] = lred;
#pragma unroll
    for (int r = 0; r < 16; r++) {
      int qr = (r & 3) + 8 * (r >> 2) + 4 * hi;
      int row = w * 32 + qr;
      po[row * 64 + l31]      = f2bf(o[0][r]);
      po[row * 64 + 32 + l31] = f2bf(o[1][r]);
    }
  }
}

// ---------------- finalize: sum chunk partials, normalize, write bf16 ------
__global__ __launch_bounds__(128) void attn_finalize(
    const unsigned short* __restrict__ pO, const float* __restrict__ pL,
    unsigned short* __restrict__ ob) {
  int bid = blockIdx.x;           // 448 = 32 bh * 14 qb(2..15)
  int qb = 2 + bid % 14;
  int bh = bid / 14;
  int b = bh >> 4, h = bh & 15;
  int cum = 0;
  for (int q = 0; q < 16; q++) {
    if (q == qb) break;
    cum += (2 * q + 5) >> 2;
  }
  int nc = (2 * qb + 5) >> 2;
  int s0 = bh * 70 + (cum - 2);

  int row = threadIdx.x;          // 128 rows
  float acc[64];
#pragma unroll
  for (int j = 0; j < 64; j++) acc[j] = 0.f;
  float l = 0.f;
  for (int c = 0; c < nc; c++) {
    const unsigned short* po = pO + (((size_t)(s0 + c)) << 13) + row * 64;
    l += pL[(s0 + c) * 128 + row];
#pragma unroll
    for (int j = 0; j < 8; j++) {
      uint4 u = *(const uint4*)(po + j * 8);
      const unsigned short* us = (const unsigned short*)&u;
#pragma unroll
      for (int e = 0; e < 8; e++) {
        unsigned int bits = (unsigned int)us[e] << 16;
        acc[j * 8 + e] += __builtin_bit_cast(float, bits);
      }
    }
  }
  float inv = 1.0f / l;
  unsigned short* dst = ob + (size_t)(b * 2048 + qb * 128 + row) * 1024 + h * 64;
  unsigned short outv[64];
#pragma unroll
  for (int c = 0; c < 64; c++) outv[c] = f2bf(acc[c] * inv);
#pragma unroll
  for (int j = 0; j < 8; j++)
    *(uint4*)(dst + j * 8) = *(const uint4*)(outv + j * 8);
}

// ---------------------------------------------------------------------------
extern "C" void kernel_launch(void* const* d_in, const int* in_sizes, int n_in,
                              void* d_out, int out_size, void* d_ws, size_t ws_size,
                              hipStream_t stream) {
  const float* x    = (const float*)d_in[0];
  const float* w_q  = (const float*)d_in[1];
  const float* w_k  = (const float*)d_in[2];
  const float* w_v  = (const float*)d_in[3];
  const float* w_p  = (const float*)d_in[4];
  const float* gain = (const float*)d_in[5];
  float* out = (float*)d_out;

  char* ws = (char*)d_ws;
  unsigned short* x_bf  = (unsigned short*)ws;                   //  8 MB
  unsigned short* wqkv  = (unsigned short*)(ws + (8u << 20));    //  3 MB
  unsigned short* wp    = (unsigned short*)(ws + (11u << 20));   //  2 MB
  unsigned short* qbuf  = (unsigned short*)(ws + (13u << 20));   //  8 MB
  unsigned short* kbuf  = (unsigned short*)(ws + (21u << 20));   //  2 MB
  unsigned short* vtbuf = (unsigned short*)(ws + (25u << 20));   //  2 MB
  unsigned short* aout  = (unsigned short*)(ws + (27u << 20));   //  8 MB
  unsigned short* pO    = (unsigned short*)(ws + (35u << 20));   // 37 MB
  float*          pL    = (float*)(ws + (73u << 20));            //  2 MB

  prep<<<6656, 256, 0, stream>>>(w_q, w_k, w_v, w_p, x, wqkv, wp, x_bf);
  gemm_qkv<<<768, 512, 0, stream>>>(x_bf, wqkv, gain, qbuf, kbuf, vtbuf);
  attn_fwd<<<2304, 256, 0, stream>>>(qbuf, kbuf, vtbuf, gain, aout, pO, pL);
  attn_finalize<<<448, 128, 0, stream>>>(pO, pL, aout);
  gemm_bt64<<<512, 512, 0, stream>>>(aout, wp, out);
}

// Round 25
// 95.230 us; speedup vs baseline: 1.0304x; 1.0039x over previous
//
#include <hip/hip_runtime.h>

// ---------------------------------------------------------------------------
// CausalSelfAttention: fake-quant-i4 weights -> QKV gemm (64x128 tile, fused
// RMSNorm+RoPE+gain epilogue + fused V-transpose) -> GQA causal flash
// attention (uniform split-KV chunks, 32x32 swapped-QK in-register softmax,
// 4 blk/CU, setprio) -> out proj (64x128 tile).  B=2 S=2048 H=16 KVH=4 D=64.
// ---------------------------------------------------------------------------

typedef __bf16 bf16x8 __attribute__((ext_vector_type(8)));
typedef float  f32x4  __attribute__((ext_vector_type(4)));
typedef float  f32x16 __attribute__((ext_vector_type(16)));
typedef int    i32x4  __attribute__((ext_vector_type(4)));

__device__ __forceinline__ unsigned short f2bf(float f) {
  __bf16 h = (__bf16)f;                     // HW RNE cvt
  return __builtin_bit_cast(unsigned short, h);
}

// ---------------- prep: fake-quant all weights + x f32->bf16, one launch ---
__global__ void prep(const float* __restrict__ wq, const float* __restrict__ wk,
                     const float* __restrict__ wv, const float* __restrict__ wp,
                     const float* __restrict__ x,
                     unsigned short* __restrict__ wqkv,
                     unsigned short* __restrict__ wpb,
                     unsigned short* __restrict__ x_bf) {
  int bid = blockIdx.x;
  int t = threadIdx.x;
  if (bid >= 2560) {
    int i = ((bid - 2560) * 256 + t) * 4;
    float4 f = *(const float4*)(x + i);
    ushort4 o;
    o.x = f2bf(f.x); o.y = f2bf(f.y); o.z = f2bf(f.z); o.w = f2bf(f.w);
    *(ushort4*)(x_bf + i) = o;
    return;
  }
  int row = bid;                            // 0..2559
  const float* s;
  unsigned short* d;
  if (row < 1024)      { s = wq + (size_t)row * 1024;          d = wqkv + (size_t)row * 1024; }
  else if (row < 1280) { s = wk + (size_t)(row - 1024) * 1024; d = wqkv + (size_t)row * 1024; }
  else if (row < 1536) { s = wv + (size_t)(row - 1280) * 1024; d = wqkv + (size_t)row * 1024; }
  else                 { s = wp + (size_t)(row - 1536) * 1024; d = wpb + (size_t)(row - 1536) * 1024; }
  float4 v = *(const float4*)(s + t * 4);
  float mx = fmaxf(fmaxf(fabsf(v.x), fabsf(v.y)), fmaxf(fabsf(v.z), fabsf(v.w)));
#pragma unroll
  for (int m = 1; m < 64; m <<= 1) mx = fmaxf(mx, __shfl_xor(mx, m));
  __shared__ float smx[4];
  if ((t & 63) == 0) smx[t >> 6] = mx;
  __syncthreads();
  mx = fmaxf(fmaxf(smx[0], smx[1]), fmaxf(smx[2], smx[3]));
  mx = fmaxf(mx, 1e-8f);
  float scale = mx / 7.0f;                  // exact div to match jnp
  float q0 = fminf(fmaxf(rintf(v.x / scale), -7.0f), 7.0f);
  float q1 = fminf(fmaxf(rintf(v.y / scale), -7.0f), 7.0f);
  float q2 = fminf(fmaxf(rintf(v.z / scale), -7.0f), 7.0f);
  float q3 = fminf(fmaxf(rintf(v.w / scale), -7.0f), 7.0f);
  ushort4 o;
  o.x = f2bf(q0 * scale); o.y = f2bf(q1 * scale);
  o.z = f2bf(q2 * scale); o.w = f2bf(q3 * scale);
  *(ushort4*)(d + t * 4) = o;
}

#define GLDS(g, l)                                                            \
  __builtin_amdgcn_global_load_lds((const __attribute__((address_space(1))) void*)(g), \
                                   (__attribute__((address_space(3))) void*)(l), 16, 0, 0)

// ---------------- proj GEMM: C[M,N] = A[M,K]*B[N,K]^T, 64x128 tile ---------
__global__ __launch_bounds__(512, 2) void gemm_bt64(
    const unsigned short* __restrict__ A, const unsigned short* __restrict__ Bw,
    float* __restrict__ C) {
  const int N = 1024, K = 1024;
  int bidx = blockIdx.x;
  int swz = (bidx & 7) * 64 + (bidx >> 3);    // XCD-chunked swizzle
  int bm = swz >> 3, bn = swz & 7;
  int tid = threadIdx.x, w = tid >> 6, lane = tid & 63;
  int l15 = lane & 15, lh = lane >> 4;
  __shared__ __align__(16) unsigned short ldsA[2][64 * 64];    // 16 KB
  __shared__ __align__(16) unsigned short ldsB[2][128 * 64];   // 32 KB
  int wr = w >> 2, wc = w & 3;
  f32x4 zero = {0.f, 0.f, 0.f, 0.f};
  f32x4 acc[2][2];
#pragma unroll
  for (int i = 0; i < 2; i++)
#pragma unroll
    for (int j = 0; j < 2; j++) acc[i][j] = zero;

  int srow = lane >> 3, schunk = (lane & 7) ^ (lane >> 3);
  const unsigned short* gA0 = A  + (size_t)(bm * 64 + srow) * K + schunk * 8;
  const unsigned short* gB0 = Bw + (size_t)(bn * 128 + srow) * K + schunk * 8;

  GLDS(gA0 + (size_t)(w * 8) * K, (unsigned short*)ldsA[0] + w * 512);
#pragma unroll
  for (int it = 0; it < 2; it++) {
    int seg = w * 2 + it;
    GLDS(gB0 + (size_t)(seg * 8) * K, (unsigned short*)ldsB[0] + seg * 512);
  }
  __syncthreads();
  int cur = 0;
  for (int kt = 0; kt < 16; kt++) {
    if (kt + 1 < 16) {
      int k0 = (kt + 1) * 64;
      GLDS(gA0 + (size_t)(w * 8) * K + k0, (unsigned short*)ldsA[cur ^ 1] + w * 512);
#pragma unroll
      for (int it = 0; it < 2; it++) {
        int seg = w * 2 + it;
        GLDS(gB0 + (size_t)(seg * 8) * K + k0, (unsigned short*)ldsB[cur ^ 1] + seg * 512);
      }
    }
    const unsigned short* cA = ldsA[cur];
    const unsigned short* cB = ldsB[cur];
#pragma unroll
    for (int ks = 0; ks < 2; ks++) {
      bf16x8 af[2], bfr[2];
#pragma unroll
      for (int fm = 0; fm < 2; fm++) {
        int row = wr * 32 + fm * 16 + l15;
        int slot = (ks * 4 + lh) ^ (row & 7);
        af[fm] = *(const bf16x8*)(cA + row * 64 + slot * 8);
      }
#pragma unroll
      for (int fn = 0; fn < 2; fn++) {
        int row = wc * 32 + fn * 16 + l15;
        int slot = (ks * 4 + lh) ^ (row & 7);
        bfr[fn] = *(const bf16x8*)(cB + row * 64 + slot * 8);
      }
#pragma unroll
      for (int fm = 0; fm < 2; fm++)
#pragma unroll
        for (int fn = 0; fn < 2; fn++)
          acc[fm][fn] = __builtin_amdgcn_mfma_f32_16x16x32_bf16(af[fm], bfr[fn], acc[fm][fn], 0, 0, 0);
    }
    __syncthreads();
    cur ^= 1;
  }
#pragma unroll
  for (int fm = 0; fm < 2; fm++) {
    int r0 = bm * 64 + wr * 32 + fm * 16 + lh * 4;
#pragma unroll
    for (int fn = 0; fn < 2; fn++) {
      int c = bn * 128 + wc * 32 + fn * 16 + l15;
#pragma unroll
      for (int reg = 0; reg < 4; reg++)
        C[(size_t)(r0 + reg) * N + c] = acc[fm][fn][reg];
    }
  }
}

// ---------------- QKV GEMM (64x128 tile, 8 waves) + fused V-transpose ------
// wave (wr=w>>1 in 0..3: 16-row group; wc=w&1: 64-col half == one head).
// Blocks with bn>=10 hold only V heads: transpose in LDS, write vt directly.
__global__ __launch_bounds__(512, 4) void gemm_qkv(
    const unsigned short* __restrict__ A, const unsigned short* __restrict__ Bw,
    const float* __restrict__ gainp,
    unsigned short* __restrict__ qb, unsigned short* __restrict__ kbp,
    unsigned short* __restrict__ vt) {
  const int K = 1024;
  int bidx = blockIdx.x;
  int swz = (bidx & 7) * 96 + (bidx >> 3);    // 768 blocks -> 96/XCD
  int bm = swz / 12, bn = swz % 12;           // bm 0..63, bn 0..11
  int tid = threadIdx.x, w = tid >> 6, lane = tid & 63;
  int l15 = lane & 15, lh = lane >> 4;
  __shared__ __align__(16) unsigned short ldsA[2][64 * 64];    // 16 KB
  __shared__ __align__(16) unsigned short ldsB[2][128 * 64];   // 32 KB
  int wr = w >> 1, wc = w & 1;
  f32x4 zero = {0.f, 0.f, 0.f, 0.f};
  f32x4 acc[4];
#pragma unroll
  for (int j = 0; j < 4; j++) acc[j] = zero;

  int srow = lane >> 3, schunk = (lane & 7) ^ (lane >> 3);
  const unsigned short* gA0 = A  + (size_t)(bm * 64 + srow) * K + schunk * 8;
  const unsigned short* gB0 = Bw + (size_t)(bn * 128 + srow) * K + schunk * 8;

  GLDS(gA0 + (size_t)(w * 8) * K, (unsigned short*)ldsA[0] + w * 512);
#pragma unroll
  for (int it = 0; it < 2; it++) {
    int seg = w * 2 + it;
    GLDS(gB0 + (size_t)(seg * 8) * K, (unsigned short*)ldsB[0] + seg * 512);
  }
  __syncthreads();
  int cur = 0;
  for (int kt = 0; kt < 16; kt++) {
    if (kt + 1 < 16) {
      int k0 = (kt + 1) * 64;
      GLDS(gA0 + (size_t)(w * 8) * K + k0, (unsigned short*)ldsA[cur ^ 1] + w * 512);
#pragma unroll
      for (int it = 0; it < 2; it++) {
        int seg = w * 2 + it;
        GLDS(gB0 + (size_t)(seg * 8) * K + k0, (unsigned short*)ldsB[cur ^ 1] + seg * 512);
      }
    }
    const unsigned short* cA = ldsA[cur];
    const unsigned short* cB = ldsB[cur];
#pragma unroll
    for (int ks = 0; ks < 2; ks++) {
      int rowA = wr * 16 + l15;
      int slotA = (ks * 4 + lh) ^ (rowA & 7);
      bf16x8 af = *(const bf16x8*)(cA + rowA * 64 + slotA * 8);
      bf16x8 bfr[4];
#pragma unroll
      for (int fn = 0; fn < 4; fn++) {
        int row = wc * 64 + fn * 16 + l15;
        int slot = (ks * 4 + lh) ^ (row & 7);
        bfr[fn] = *(const bf16x8*)(cB + row * 64 + slot * 8);
      }
#pragma unroll
      for (int fn = 0; fn < 4; fn++)
        acc[fn] = __builtin_amdgcn_mfma_f32_16x16x32_bf16(af, bfr[fn], acc[fn], 0, 0, 0);
    }
    __syncthreads();
    cur ^= 1;
  }

  // ---- fused epilogue ----
  int hid = bn * 2 + wc;
  int rbase = bm * 64 + wr * 16;
  if (bn >= 10) {
    // whole block is V heads (hid 20..23): LDS transpose, write vt [d][s]
    unsigned short* ldsT = (unsigned short*)ldsB;   // 128*68 shorts = 17 KB
    __syncthreads();                                 // main-loop LDS reads done
#pragma unroll
    for (int reg = 0; reg < 4; reg++) {
      int sl = wr * 16 + lh * 4 + reg;               // 0..63 (local row)
#pragma unroll
      for (int fn = 0; fn < 4; fn++) {
        int db = wc * 64 + fn * 16 + l15;            // 0..127 (head-pair col)
        ldsT[db * 68 + sl] = f2bf(acc[fn][reg]);
      }
    }
    __syncthreads();
    int db = tid >> 2;                               // 0..127
    int sseg = (tid & 3) * 16;                       // 0,16,32,48
    int vh = (bn - 10) * 2 + (db >> 6);              // 0..3
    int d = db & 63;
    int gr = bm * 64 + sseg;
    int bb = gr >> 11, sgl = gr & 2047;
    unsigned short* dst = vt + ((size_t)(bb * 4 + vh) * 64 + d) * 2048 + sgl;
#pragma unroll
    for (int j = 0; j < 16; j += 4)
      *(ushort4*)(dst + j) = *(const ushort4*)(ldsT + db * 68 + sseg + j);
  } else {
    bool isq = hid < 16;
    float gn = isq ? gainp[hid] : 1.0f;
    float invf0 = __expf(-0.28782313662425572f * (float)l15);         // ln(1e4)/32
    float invf1 = __expf(-0.28782313662425572f * (float)(l15 + 16));
#pragma unroll
    for (int reg = 0; reg < 4; reg++) {
      float y0 = acc[0][reg], y1 = acc[1][reg];
      float y2 = acc[2][reg], y3 = acc[3][reg];
      float ss = y0 * y0 + y1 * y1 + y2 * y2 + y3 * y3;
      ss += __shfl_xor(ss, 1); ss += __shfl_xor(ss, 2);
      ss += __shfl_xor(ss, 4); ss += __shfl_xor(ss, 8);
      float rn = rsqrtf(ss * 0.015625f + 1.1920929e-7f);
      y0 *= rn; y1 *= rn; y2 *= rn; y3 *= rn;
      int r = rbase + lh * 4 + reg;
      int b = r >> 11, s = r & 2047;
      float c0, s0n, c1, s1n;
      __sincosf((float)s * invf0, &s0n, &c0);
      __sincosf((float)s * invf1, &s1n, &c1);
      float o0 = (y0 * c0 + y2 * s0n) * gn;
      float o1 = (y1 * c1 + y3 * s1n) * gn;
      float o2 = (y2 * c0 - y0 * s0n) * gn;
      float o3 = (y3 * c1 - y1 * s1n) * gn;
      unsigned short* dst = isq
        ? qb  + (((size_t)(b * 16 + hid) * 2048 + s) << 6)
        : kbp + (((size_t)(b * 4 + (hid - 16)) * 2048 + s) << 6);
      dst[l15]      = f2bf(o0);
      dst[l15 + 16] = f2bf(o1);
      dst[l15 + 32] = f2bf(o2);
      dst[l15 + 48] = f2bf(o3);
    }
  }
}

// ---------------- causal flash attention (32x32 swapped-QK, in-reg P) ------
template<bool MASK>
__device__ __forceinline__ void attn_tile(
    int kv0, int q0, int l31, int hi, float M2,
    const unsigned short* ldsK, const unsigned short* ldsV,
    const bf16x8 (&qf)[4], float& lsum, f32x16 (&o)[2]) {
  const float K2 = 0.18033688011112042f;  // 0.125 * log2(e)
  f32x16 sc[2];
#pragma unroll
  for (int i = 0; i < 16; i++) { sc[0][i] = 0.f; sc[1][i] = 0.f; }
  // --- QK^T swapped: A=K (rows=kv), B=Q (cols=q) ---
  __builtin_amdgcn_s_setprio(1);
#pragma unroll
  for (int ks = 0; ks < 4; ks++) {
    int slot0 = (2 * ks + hi) ^ (l31 & 7);
    bf16x8 kf0 = *(const bf16x8*)(ldsK + l31 * 64 + slot0 * 8);
    int row1 = 32 + l31;
    int slot1 = (2 * ks + hi) ^ (row1 & 7);
    bf16x8 kf1 = *(const bf16x8*)(ldsK + row1 * 64 + slot1 * 8);
    sc[0] = __builtin_amdgcn_mfma_f32_32x32x16_bf16(kf0, qf[ks], sc[0], 0, 0, 0);
    sc[1] = __builtin_amdgcn_mfma_f32_32x32x16_bf16(kf1, qf[ks], sc[1], 0, 0, 0);
  }
  __builtin_amdgcn_s_setprio(0);
  // --- per-fn: softmax quarter then its PV pair (overlap VALU with MFMA) ---
  float ls = 0.f;
  int rowq = q0 + l31;
#pragma unroll
  for (int fn = 0; fn < 2; fn++) {
    unsigned int Wp[4][2];
#pragma unroll
    for (int g = 0; g < 4; g++) {
      float p4[4];
#pragma unroll
      for (int m = 0; m < 4; m++) {
        int r = 4 * g + m;
        float s = __builtin_fmaf(sc[fn][r], K2, -M2);
        if (MASK) {
          int col = kv0 + fn * 32 + m + 8 * g + 4 * hi;  // crow(r,hi)
          if (col > rowq) s = -1e30f;
        }
        float p = __builtin_amdgcn_exp2f(s);
        ls += p;
        p4[m] = p;
      }
      asm("v_cvt_pk_bf16_f32 %0, %1, %2" : "=v"(Wp[g][0]) : "v"(p4[0]), "v"(p4[1]));
      asm("v_cvt_pk_bf16_f32 %0, %1, %2" : "=v"(Wp[g][1]) : "v"(p4[2]), "v"(p4[3]));
    }
    __builtin_amdgcn_s_setprio(1);
#pragma unroll
    for (int e = 0; e < 2; e++) {
      int ksg = fn * 2 + e;
      unsigned int u0 = Wp[2 * e][0], u1 = Wp[2 * e + 1][0];
      unsigned int u2 = Wp[2 * e][1], u3 = Wp[2 * e + 1][1];
      asm("v_permlane32_swap_b32 %0, %1" : "+v"(u0), "+v"(u1));
      asm("v_permlane32_swap_b32 %0, %1" : "+v"(u2), "+v"(u3));
      i32x4 pw;
      pw[0] = (int)u0; pw[1] = (int)u2; pw[2] = (int)u1; pw[3] = (int)u3;
      bf16x8 pf = __builtin_bit_cast(bf16x8, pw);
      int slot0 = (2 * ksg + hi) ^ (l31 & 7);
      bf16x8 v0 = *(const bf16x8*)(ldsV + l31 * 64 + slot0 * 8);
      int row1 = 32 + l31;
      int slot1 = (2 * ksg + hi) ^ (row1 & 7);
      bf16x8 v1 = *(const bf16x8*)(ldsV + row1 * 64 + slot1 * 8);
      o[0] = __builtin_amdgcn_mfma_f32_32x32x16_bf16(pf, v0, o[0], 0, 0, 0);
      o[1] = __builtin_amdgcn_mfma_f32_32x32x16_bf16(pf, v1, o[1], 0, 0, 0);
    }
    __builtin_amdgcn_s_setprio(0);
  }
  lsum += ls;
}

__global__ __launch_bounds__(256, 4) void attn_fwd(
    const unsigned short* __restrict__ qbuf, const unsigned short* __restrict__ kb,
    const unsigned short* __restrict__ vtb, const float* __restrict__ gain,
    unsigned short* __restrict__ ob, unsigned short* __restrict__ pO,
    float* __restrict__ pL) {
  int bid = blockIdx.x;
  int cid = 71 - (bid >> 5);      // heavy chunks dispatch first
  int bh = bid & 31;
  int b = bh >> 4, h = bh & 15;
  int qb = 0, cum = 0;
  for (int q = 0; q < 16; q++) {
    int ncq = (2 * q + 5) >> 2;
    if (cid < cum + ncq) { qb = q; break; }
    cum += ncq;
  }
  int nt = 2 * qb + 2;
  int nc = (2 * qb + 5) >> 2;
  int ch = cid - cum;
  int base = nt / nc, rem = nt % nc;
  int t0 = ch * base + (ch < rem ? ch : rem);
  int t1 = t0 + base + (ch < rem ? 1 : 0);
  bool direct = (nc == 1);        // qb 0,1

  int tid = threadIdx.x;
  int w = tid >> 6, lane = tid & 63;
  int l31 = lane & 31, hi = lane >> 5;
  int q0 = qb * 128 + w * 32;
  int kvh = h >> 2;
  const unsigned short* Q  = qbuf + (size_t)(b * 16 + h) * (2048 * 64);
  const unsigned short* Kg = kb   + (size_t)(b * 4 + kvh) * (2048 * 64);
  const unsigned short* Vg = vtb  + (size_t)(b * 4 + kvh) * (64 * 2048);

  __shared__ __align__(16) unsigned short ldsK[2][64 * 64];    // 16 KB
  __shared__ __align__(16) unsigned short ldsV[2][64 * 64];    // 16 KB

  float gn = gain[h];
  float M2 = __builtin_fmaf(fabsf(gn), 1.46f, 0.02f);  // static max bound

  // Q as B-frags: col=l31 (q row), k = 16ks + 8hi + j
  bf16x8 qf[4];
#pragma unroll
  for (int ks = 0; ks < 4; ks++)
    qf[ks] = *(const bf16x8*)(Q + (size_t)(q0 + l31) * 64 + ks * 16 + hi * 8);

  f32x16 o[2];
#pragma unroll
  for (int i = 0; i < 16; i++) { o[0][i] = 0.f; o[1][i] = 0.f; }
  float lsum = 0.f;

  int srow = lane >> 3;
  int schunk = (lane & 7) ^ (lane >> 3);
  int full = q0 >> 6;

#pragma unroll
  for (int it = 0; it < 2; it++) {
    int seg = w * 2 + it;
    GLDS(Kg + (size_t)(t0 * 64 + seg * 8 + srow) * 64 + schunk * 8,
         (unsigned short*)ldsK[0] + seg * 512);
    GLDS(Vg + (size_t)(seg * 8 + srow) * 2048 + t0 * 64 + schunk * 8,
         (unsigned short*)ldsV[0] + seg * 512);
  }
  __syncthreads();
  int cur = 0;
  for (int t = t0; t < t1; t++) {
    int kv0 = t * 64;
    if (t + 1 < t1) {
      int kn = kv0 + 64;
#pragma unroll
      for (int it = 0; it < 2; it++) {
        int seg = w * 2 + it;
        GLDS(Kg + (size_t)(kn + seg * 8 + srow) * 64 + schunk * 8,
             (unsigned short*)ldsK[cur ^ 1] + seg * 512);
        GLDS(Vg + (size_t)(seg * 8 + srow) * 2048 + kn + schunk * 8,
             (unsigned short*)ldsV[cur ^ 1] + seg * 512);
      }
    }
    if (t < full)
      attn_tile<false>(kv0, q0, l31, hi, M2, ldsK[cur], ldsV[cur], qf, lsum, o);
    else if (kv0 <= q0 + 31)
      attn_tile<true>(kv0, q0, l31, hi, M2, ldsK[cur], ldsV[cur], qf, lsum, o);
    __syncthreads();
    cur ^= 1;
  }

  float lred = lsum + __shfl_xor(lsum, 32);   // full row sum (q = l31)
  if (direct) {
    float linv = 1.0f / lred;
#pragma unroll
    for (int r = 0; r < 16; r++) {
      int qr = (r & 3) + 8 * (r >> 2) + 4 * hi;     // q row within 32
      float iv = __shfl(linv, qr);
      size_t rb = (size_t)(b * 2048 + q0 + qr) * 1024 + h * 64;
      ob[rb + l31]      = f2bf(o[0][r] * iv);
      ob[rb + 32 + l31] = f2bf(o[1][r] * iv);
    }
  } else {
    int slot = bh * 70 + (cid - 2);
    unsigned short* po = pO + ((size_t)slot << 13);   // 128*64 bf16, plain
    float* pl = pL + slot * 128;
    if (lane < 32) pl[w * 32 + l31] = lred;
#pragma unroll
    for (int r = 0; r < 16; r++) {
      int qr = (r & 3) + 8 * (r >> 2) + 4 * hi;
      int row = w * 32 + qr;
      po[row * 64 + l31]      = f2bf(o[0][r]);
      po[row * 64 + 32 + l31] = f2bf(o[1][r]);
    }
  }
}

// ---------------- finalize: sum chunk partials, normalize, write bf16 ------
__global__ __launch_bounds__(128) void attn_finalize(
    const unsigned short* __restrict__ pO, const float* __restrict__ pL,
    unsigned short* __restrict__ ob) {
  int bid = blockIdx.x;           // 448 = 32 bh * 14 qb(2..15)
  int qb = 2 + bid % 14;
  int bh = bid / 14;
  int b = bh >> 4, h = bh & 15;
  int cum = 0;
  for (int q = 0; q < 16; q++) {
    if (q == qb) break;
    cum += (2 * q + 5) >> 2;
  }
  int nc = (2 * qb + 5) >> 2;
  int s0 = bh * 70 + (cum - 2);

  int row = threadIdx.x;          // 128 rows
  float acc[64];
#pragma unroll
  for (int j = 0; j < 64; j++) acc[j] = 0.f;
  float l = 0.f;
  for (int c = 0; c < nc; c++) {
    const unsigned short* po = pO + (((size_t)(s0 + c)) << 13) + row * 64;
    l += pL[(s0 + c) * 128 + row];
#pragma unroll
    for (int j = 0; j < 8; j++) {
      uint4 u = *(const uint4*)(po + j * 8);
      const unsigned short* us = (const unsigned short*)&u;
#pragma unroll
      for (int e = 0; e < 8; e++) {
        unsigned int bits = (unsigned int)us[e] << 16;
        acc[j * 8 + e] += __builtin_bit_cast(float, bits);
      }
    }
  }
  float inv = 1.0f / l;
  unsigned short* dst = ob + (size_t)(b * 2048 + qb * 128 + row) * 1024 + h * 64;
  unsigned short outv[64];
#pragma unroll
  for (int c = 0; c < 64; c++) outv[c] = f2bf(acc[c] * inv);
#pragma unroll
  for (int j = 0; j < 8; j++)
    *(uint4*)(dst + j * 8) = *(const uint4*)(outv + j * 8);
}

// ---------------------------------------------------------------------------
extern "C" void kernel_launch(void* const* d_in, const int* in_sizes, int n_in,
                              void* d_out, int out_size, void* d_ws, size_t ws_size,
                              hipStream_t stream) {
  const float* x    = (const float*)d_in[0];
  const float* w_q  = (const float*)d_in[1];
  const float* w_k  = (const float*)d_in[2];
  const float* w_v  = (const float*)d_in[3];
  const float* w_p  = (const float*)d_in[4];
  const float* gain = (const float*)d_in[5];
  float* out = (float*)d_out;

  char* ws = (char*)d_ws;
  unsigned short* x_bf  = (unsigned short*)ws;                   //  8 MB
  unsigned short* wqkv  = (unsigned short*)(ws + (8u << 20));    //  3 MB
  unsigned short* wp    = (unsigned short*)(ws + (11u << 20));   //  2 MB
  unsigned short* qbuf  = (unsigned short*)(ws + (13u << 20));   //  8 MB
  unsigned short* kbuf  = (unsigned short*)(ws + (21u << 20));   //  2 MB
  unsigned short* vtbuf = (unsigned short*)(ws + (25u << 20));   //  2 MB
  unsigned short* aout  = (unsigned short*)(ws + (27u << 20));   //  8 MB
  unsigned short* pO    = (unsigned short*)(ws + (35u << 20));   // 37 MB
  float*          pL    = (float*)(ws + (73u << 20));            //  2 MB

  prep<<<6656, 256, 0, stream>>>(w_q, w_k, w_v, w_p, x, wqkv, wp, x_bf);
  gemm_qkv<<<768, 512, 0, stream>>>(x_bf, wqkv, gain, qbuf, kbuf, vtbuf);
  attn_fwd<<<2304, 256, 0, stream>>>(qbuf, kbuf, vtbuf, gain, aout, pO, pL);
  attn_finalize<<<448, 128, 0, stream>>>(pO, pL, aout);
  gemm_bt64<<<512, 512, 0, stream>>>(aout, wp, out);
}